// Round 2
// baseline (275.086 us; speedup 1.0000x reference)
//
#include <hip/hip_runtime.h>
#include <stdint.h>

typedef short short8 __attribute__((ext_vector_type(8)));
typedef float f32x4 __attribute__((ext_vector_type(4)));
typedef float f32x16 __attribute__((ext_vector_type(16)));
typedef unsigned int uint2v __attribute__((ext_vector_type(2)));
typedef unsigned int uint4v __attribute__((ext_vector_type(4)));

__device__ __forceinline__ unsigned short f2bf(float f) {
    unsigned int u = __float_as_uint(f);
    u += 0x7fffu + ((u >> 16) & 1u);   // round-to-nearest-even
    return (unsigned short)(u >> 16);
}

// async global->LDS, 16B per lane; lds base must be wave-uniform (HW adds lane*16)
__device__ __forceinline__ void gld_lds16(const unsigned short* g, unsigned short* l) {
    __builtin_amdgcn_global_load_lds((const __attribute__((address_space(1))) unsigned int*)g,
                                     (__attribute__((address_space(3))) unsigned int*)l,
                                     16, 0, 0);
}

// Q pre-scale: fold attn scale (1/8) and log2(e) into Q so attn softmax uses exp2 directly.
#define QSCL 0.18033688011112042f

// ---------- fused fp32->bf16 converts + bias concat (one dispatch) ----------
__global__ __launch_bounds__(256) void cvt_all(const float* __restrict__ x,
                                               const float* __restrict__ qw, const float* __restrict__ kw,
                                               const float* __restrict__ vw, const float* __restrict__ ow,
                                               const float* __restrict__ qb, const float* __restrict__ kb,
                                               const float* __restrict__ vb,
                                               unsigned short* __restrict__ Xb,
                                               unsigned short* __restrict__ Wqkv,
                                               unsigned short* __restrict__ Owb,
                                               float* __restrict__ bqkv) {
    int i = blockIdx.x * 256 + threadIdx.x;     // float4 index
    const float* src; uint2* dst; int j;
    if (i < 2097152)      { src = x;  dst = (uint2*)Xb;                j = i; }
    else if (i < 2359296) { src = qw; dst = (uint2*)Wqkv;              j = i - 2097152; }
    else if (i < 2621440) { src = kw; dst = (uint2*)(Wqkv + 1048576);  j = i - 2359296; }
    else if (i < 2883584) { src = vw; dst = (uint2*)(Wqkv + 2097152);  j = i - 2621440; }
    else if (i < 3145728) { src = ow; dst = (uint2*)Owb;               j = i - 2883584; }
    else {
        int t = i - 3145728;          // 0..767 : fp32 bias copies
        const float4* bs = (t < 256) ? (const float4*)qb : (t < 512) ? (const float4*)kb : (const float4*)vb;
        ((float4*)bqkv)[t] = bs[t & 255];
        return;
    }
    float4 v = ((const float4*)src)[j];
    unsigned int lo = (unsigned int)f2bf(v.x) | ((unsigned int)f2bf(v.y) << 16);
    unsigned int hi = (unsigned int)f2bf(v.z) | ((unsigned int)f2bf(v.w) << 16);
    dst[j] = make_uint2(lo, hi);
}

// ---------- bf16 NT GEMM, 256x256 tile, BK=64, 8 waves, 8-phase counted-vmcnt pipeline ----------
// C[M,N] = A[M,K] @ B[N,K]^T + bias[N].
// LDS 128 KiB: A/B double-buffered 256x64 tiles, granule-xor swizzle (conflict-free, same as 128^2 ver).
// Per iter: 2 K-tiles (buf0 even, buf1 odd), 8 phases. Each phase: ds_read subtile || stage 1
// half-tile (2 gld_lds16/thread) -> barrier -> 16 MFMA -> barrier. Counted vmcnt(4) at P4/P8 only
// (2 half-tiles in flight); raw s_barrier (no __syncthreads -> no vmcnt(0) drain).
// Stage schedule (iter j): P1:As1h0(t1) P2:As1h1(t1) P3:Bs0h0(t2) P4:Bs0h1(t2)
//                          P5:As0h0(t2) P6:As0h1(t2) P7:Bs1h0(t3) P8:Bs1h1(t3)
// Safety: each slot staged >=1 full barrier after its last ds_read (A halves read P1&P3; B halves P1&P2).
// MODE 0: C0 = fp32 [M][N].
// MODE 1 (QKV): col<1024 -> bf16 Q (pre-scaled by QSCL); col<2048 -> bf16 K; col>=2048 -> Vt transposed.

#define BAR() do { __builtin_amdgcn_sched_barrier(0); __builtin_amdgcn_s_barrier(); \
                   __builtin_amdgcn_sched_barrier(0); } while (0)

#define RD_A(BI, MH) \
    _Pragma("unroll") for (int mtl = 0; mtl < 4; ++mtl) { \
        int m = wm * 128 + (MH) * 64 + mtl * 16 + l15; \
        af[mtl][0] = *(const short8*)&As[BI][m * 64 + ((quad ^ (m & 7)) << 3)]; \
        af[mtl][1] = *(const short8*)&As[BI][m * 64 + (((4 + quad) ^ (m & 7)) << 3)]; \
    }

#define RD_B(BI, NH) \
    _Pragma("unroll") for (int ntl = 0; ntl < 2; ++ntl) { \
        int n = wn * 64 + ((NH) * 2 + ntl) * 16 + l15; \
        bfv[(NH) * 2 + ntl][0] = *(const short8*)&Bs[BI][n * 64 + ((quad ^ (n & 7)) << 3)]; \
        bfv[(NH) * 2 + ntl][1] = *(const short8*)&Bs[BI][n * 64 + (((4 + quad) ^ (n & 7)) << 3)]; \
    }

#define MFMA_Q(MH, NH) \
    __builtin_amdgcn_s_setprio(1); \
    _Pragma("unroll") for (int mtl = 0; mtl < 4; ++mtl) \
    _Pragma("unroll") for (int ntl = 0; ntl < 2; ++ntl) { \
        const int nt_ = (NH) * 2 + ntl, mt_ = (MH) * 4 + mtl; \
        acc[mt_][nt_] = __builtin_amdgcn_mfma_f32_16x16x32_bf16(af[mtl][0], bfv[nt_][0], acc[mt_][nt_], 0, 0, 0); \
        acc[mt_][nt_] = __builtin_amdgcn_mfma_f32_16x16x32_bf16(af[mtl][1], bfv[nt_][1], acc[mt_][nt_], 0, 0, 0); \
    } \
    __builtin_amdgcn_s_setprio(0);

// stage one 128x64 half-tile (16 KiB): 2 x gld_lds16 per thread
#define STAGE(DST, BI, H, SRC, KT) \
    _Pragma("unroll") for (int i_ = 0; i_ < 2; ++i_) { \
        int G_ = i_ * 512 + tid; \
        int r_ = G_ >> 3, g_ = G_ & 7, gs_ = g_ ^ (r_ & 7); \
        gld_lds16((SRC) + (size_t)((H) * 128 + r_) * K + (KT) * 64 + gs_ * 8, \
                  &DST[BI][(H) * 8192 + (i_ * 512 + w * 64) * 8]); \
    }

template<int MODE>
__global__ __launch_bounds__(512, 2) void gemm256(const unsigned short* __restrict__ A,
                                                  const unsigned short* __restrict__ Bm,
                                                  const float* __restrict__ bias,
                                                  void* __restrict__ C0,
                                                  unsigned short* __restrict__ VtOut,
                                                  int M, int N, int K)
{
    __shared__ __align__(16) unsigned short As[2][256 * 64];
    __shared__ __align__(16) unsigned short Bs[2][256 * 64];
    const int tid  = threadIdx.x;
    const int bm   = blockIdx.x, bn = blockIdx.y;
    const int lane = tid & 63, w = tid >> 6;
    const int wm   = w >> 2, wn = w & 3;              // 2 M-waves x 4 N-waves
    const int quad = lane >> 4, l15 = lane & 15;

    const unsigned short* Ag = A  + (size_t)(bm * 256) * K;
    const unsigned short* Bg = Bm + (size_t)(bn * 256) * K;

    f32x4 acc[8][4];
#pragma unroll
    for (int mt = 0; mt < 8; mt++)
#pragma unroll
        for (int nt = 0; nt < 4; nt++)
            acc[mt][nt] = (f32x4){0.f, 0.f, 0.f, 0.f};

    short8 af[4][2];    // current A m-half fragments
    short8 bfv[4][2];   // all four nt B fragments (both halves kept live)

    const int NI = K >> 7;     // iterations; 2 K-tiles each

    // ---- prologue: tile0 full + tile1 B halves; leaves {Bs1h0,Bs1h1} in flight ----
    STAGE(As, 0, 0, Ag, 0); STAGE(As, 0, 1, Ag, 0);
    STAGE(Bs, 0, 0, Bg, 0); STAGE(Bs, 0, 1, Bg, 0);
    STAGE(Bs, 1, 0, Bg, 1); STAGE(Bs, 1, 1, Bg, 1);
    asm volatile("s_waitcnt vmcnt(4)" ::: "memory");
    BAR();

    for (int j = 0; j < NI; ++j) {
        const int t1 = 2 * j + 1, t2 = 2 * j + 2, t3 = 2 * j + 3;
        const bool more = (j < NI - 1);
        // ---- P1 ----
        RD_A(0, 0); RD_B(0, 0);
        __builtin_amdgcn_sched_barrier(0);
        STAGE(As, 1, 0, Ag, t1);
        BAR();
        MFMA_Q(0, 0);
        BAR();
        // ---- P2 ----
        RD_B(0, 1);
        __builtin_amdgcn_sched_barrier(0);
        STAGE(As, 1, 1, Ag, t1);
        BAR();
        MFMA_Q(0, 1);
        BAR();
        // ---- P3 ----
        RD_A(0, 1);
        __builtin_amdgcn_sched_barrier(0);
        if (more) { STAGE(Bs, 0, 0, Bg, t2); }
        BAR();
        MFMA_Q(1, 0);
        BAR();
        // ---- P4 ----
        if (more) { STAGE(Bs, 0, 1, Bg, t2); }
        BAR();
        MFMA_Q(1, 1);
        if (more) { asm volatile("s_waitcnt vmcnt(4)" ::: "memory"); }
        else      { asm volatile("s_waitcnt vmcnt(0)" ::: "memory"); }
        BAR();
        // ---- P5 ----
        RD_A(1, 0); RD_B(1, 0);
        __builtin_amdgcn_sched_barrier(0);
        if (more) { STAGE(As, 0, 0, Ag, t2); }
        BAR();
        MFMA_Q(0, 0);
        BAR();
        // ---- P6 ----
        RD_B(1, 1);
        __builtin_amdgcn_sched_barrier(0);
        if (more) { STAGE(As, 0, 1, Ag, t2); }
        BAR();
        MFMA_Q(0, 1);
        BAR();
        // ---- P7 ----
        RD_A(1, 1);
        __builtin_amdgcn_sched_barrier(0);
        if (more) { STAGE(Bs, 1, 0, Bg, t3); }
        BAR();
        MFMA_Q(1, 0);
        BAR();
        // ---- P8 ----
        if (more) { STAGE(Bs, 1, 1, Bg, t3); }
        BAR();
        MFMA_Q(1, 1);
        if (more) { asm volatile("s_waitcnt vmcnt(4)" ::: "memory"); }
        BAR();
    }

    // ---- epilogue: D row = quad*4+reg, col = l15 ----
    const int row0 = bm * 256 + wm * 128, col0 = bn * 256 + wn * 64;
#pragma unroll
    for (int nt = 0; nt < 4; nt++) {
        int col = col0 + nt * 16 + l15;
        float bv = bias[col];
#pragma unroll
        for (int mt = 0; mt < 8; mt++) {
            if (MODE == 1 && col >= 2048) {
                // V: write transposed Vt[(b*1024 + (col-2048))*2048 + t]
                int row = row0 + mt * 16 + quad * 4;
                int b = row >> 11, t = row & 2047;
                ushort4 pk;
                pk.x = f2bf(acc[mt][nt][0] + bv);
                pk.y = f2bf(acc[mt][nt][1] + bv);
                pk.z = f2bf(acc[mt][nt][2] + bv);
                pk.w = f2bf(acc[mt][nt][3] + bv);
                *(ushort4*)(VtOut + (size_t)(b * 1024 + (col - 2048)) * 2048 + t) = pk;
            } else {
#pragma unroll
                for (int r = 0; r < 4; r++) {
                    int row = row0 + mt * 16 + quad * 4 + r;
                    float v = acc[mt][nt][r] + bv;
                    if (MODE == 1) {
                        if (col < 1024) v *= QSCL;
                        ((unsigned short*)C0)[(size_t)row * 2048 + col] = f2bf(v);
                    } else {
                        ((float*)C0)[(size_t)row * N + col] = v;
                    }
                }
            }
        }
    }
}

// ---------- MFMA causal flash attention, 32x32 tiles, fully in-register softmax ----------
// QK: (8192, 2048) bf16 rows = (b,t), cols [0,1024)=Q (pre-scaled by QSCL), [1024,2048)=K.
// Vt: [b*16+h][d][t] bf16. Block 256 = 4 waves; wave owns 32 q rows. Grid (64 bh, 16 qtiles).
// Per 64-key tile: K (64x64 [key][d]) and V^T (64x64 [d][t]) staged via global_load_lds(16),
// xor-granule swizzle, double-buffered, one barrier per tile.
// S^T = K@Q^T via mfma_32x32x16 (2 key-subtiles x 4 d-slices). Lane holds 16 P-values of one
// q-column; exp2 -> perm-pack to bf16 -> 4x permlane32_swap builds PV B-fragments in registers
// (no P LDS round-trip). l via VALU tree-sum + one final permlane swap.
// Fixed-max softmax: p = exp2(s) directly (scores bounded; constant max cancels in O/l).
#define NEG_RAW (-1e30f)
__global__ __launch_bounds__(256, 4) void attn_mfma(const unsigned short* __restrict__ QK,
                                                    const unsigned short* __restrict__ Vt,
                                                    unsigned short* __restrict__ O)
{
    __shared__ __align__(16) unsigned short Kb[2][64 * 64];
    __shared__ __align__(16) unsigned short Vb[2][64 * 64];
    const int tid  = threadIdx.x;
    const int lane = tid & 63, w = tid >> 6;
    const int hi   = lane >> 5, l31 = lane & 31;
    const int s7   = lane & 7;
    const int bh   = blockIdx.x;
    const int b    = bh >> 4, h = bh & 15;
    const int qt   = (int)gridDim.y - 1 - (int)blockIdx.y;   // longest first
    const int qbase = qt * 128 + w * 32;                     // this wave's first q row

    const unsigned short* Qp = QK + (size_t)(b * 2048) * 2048 + h * 64;
    const unsigned short* Kp = Qp + 1024;
    const unsigned short* Vp = Vt + (size_t)(bh * 64) * 2048;

    // Q B-fragments (32x32x16): col q = l31, k = dk*16 + hi*8 + j
    short8 qf[4];
    {
        const unsigned short* qrow = Qp + (size_t)(qbase + l31) * 2048 + hi * 8;
#pragma unroll
        for (int dk = 0; dk < 4; dk++)
            qf[dk] = *(const short8*)(qrow + dk * 16);
    }

    f32x16 oacc[2];   // O^T: oacc[dsub], row d = dsub*32 + (r&3)+8*(r>>2)+4*hi, col q = l31
#pragma unroll
    for (int i = 0; i < 2; i++)
#pragma unroll
        for (int r = 0; r < 16; r++) oacc[i][r] = 0.f;
    float lsum = 0.f;

    const int ktend   = 2 * qt + 1;               // block processes keys [0, (qt+1)*128)
    const int ktmax_w = (qbase + 31) >> 6;        // last tile this wave computes on

    // ---- stage tile 0 ----
#pragma unroll
    for (int i = 0; i < 2; i++) {
        int G = i * 256 + tid;
        int r = G >> 3, g = G & 7, gs = g ^ (r & 7);
        int Gb = i * 256 + (w << 6);
        gld_lds16(Kp + (size_t)r * 2048 + gs * 8, &Kb[0][Gb * 8]);
        gld_lds16(Vp + (size_t)r * 2048 + gs * 8, &Vb[0][Gb * 8]);
    }
    __syncthreads();

    for (int kt = 0; kt <= ktend; ++kt) {
        const int cur = kt & 1;
        // ---- prefetch tile kt+1 into the other buffer ----
        if (kt < ktend) {
            const unsigned short* Kn = Kp + (size_t)((kt + 1) * 64) * 2048;
            const unsigned short* Vn = Vp + (kt + 1) * 64;
#pragma unroll
            for (int i = 0; i < 2; i++) {
                int G = i * 256 + tid;
                int r = G >> 3, g = G & 7, gs = g ^ (r & 7);
                int Gb = i * 256 + (w << 6);
                gld_lds16(Kn + (size_t)r * 2048 + gs * 8, &Kb[cur ^ 1][Gb * 8]);
                gld_lds16(Vn + (size_t)r * 2048 + gs * 8, &Vb[cur ^ 1][Gb * 8]);
            }
        }
        // ---- compute on buffer cur ----
        if (kt <= ktmax_w) {
            __builtin_amdgcn_s_setprio(1);
            const unsigned short* Kc = Kb[cur];
            const unsigned short* Vc = Vb[cur];
            const int kbase = kt * 64;
#pragma unroll
            for (int sub = 0; sub < 2; sub++) {
                const int kb0 = kbase + sub * 32;
                if (kb0 > qbase + 31) continue;          // subtile fully masked
                // ---- S^T (32 keys x 32 q) ----
                f32x16 sacc;
#pragma unroll
                for (int r = 0; r < 16; r++) sacc[r] = 0.f;
                const unsigned short* kr = &Kc[(sub * 32 + l31) * 64];
#pragma unroll
                for (int dk = 0; dk < 4; dk++) {
                    short8 kf = *(const short8*)(kr + (((dk * 2 + hi) ^ s7) << 3));
                    sacc = __builtin_amdgcn_mfma_f32_32x32x16_bf16(kf, qf[dk], sacc, 0, 0, 0);
                }
                // ---- causal mask (diag subtile only) ----
                if (kb0 + 31 > qbase) {
                    const int qg = qbase + l31;
                    const int kb = kb0 + 4 * hi;
#pragma unroll
                    for (int r = 0; r < 16; r++) {
                        int key = kb + (r & 3) + 8 * (r >> 2);
                        if (key > qg) sacc[r] = NEG_RAW;
                    }
                }
                // ---- p = exp2(s); l partial sum ----
#pragma unroll
                for (int r = 0; r < 16; r++) sacc[r] = __builtin_exp2f(sacc[r]);
                {
                    float s0 = (sacc[0] + sacc[1]) + (sacc[2] + sacc[3]);
                    float s1 = (sacc[4] + sacc[5]) + (sacc[6] + sacc[7]);
                    float s2 = (sacc[8] + sacc[9]) + (sacc[10] + sacc[11]);
                    float s3 = (sacc[12] + sacc[13]) + (sacc[14] + sacc[15]);
                    lsum += (s0 + s1) + (s2 + s3);
                }
                // ---- pack pairs to bf16 (truncating perm), exchange halves -> PV B-frags ----
                unsigned int pk[8];
#pragma unroll
                for (int t2 = 0; t2 < 8; t2++)
                    pk[t2] = __builtin_amdgcn_perm(__float_as_uint(sacc[2 * t2 + 1]),
                                                   __float_as_uint(sacc[2 * t2]), 0x07060302u);
                uint2v r0 = __builtin_amdgcn_permlane32_swap(pk[0], pk[2], false, false);
                uint2v r1 = __builtin_amdgcn_permlane32_swap(pk[1], pk[3], false, false);
                uint2v r2 = __builtin_amdgcn_permlane32_swap(pk[4], pk[6], false, false);
                uint2v r3 = __builtin_amdgcn_permlane32_swap(pk[5], pk[7], false, false);
                short8 pf[2];
                { uint4v u; u.x = r0.x; u.y = r1.x; u.z = r0.y; u.w = r1.y; pf[0] = __builtin_bit_cast(short8, u); }
                { uint4v u; u.x = r2.x; u.y = r3.x; u.z = r2.y; u.w = r3.y; pf[1] = __builtin_bit_cast(short8, u); }
                // ---- O^T += V^T @ P^T ----
#pragma unroll
                for (int kv = 0; kv < 2; kv++) {
#pragma unroll
                    for (int dsub = 0; dsub < 2; dsub++) {
                        const int d = dsub * 32 + l31;
                        short8 vf = *(const short8*)&Vc[d * 64 + (((sub * 4 + kv * 2 + hi) ^ s7) << 3)];
                        oacc[dsub] = __builtin_amdgcn_mfma_f32_32x32x16_bf16(vf, pf[kv], oacc[dsub], 0, 0, 0);
                    }
                }
            }
            __builtin_amdgcn_s_setprio(0);
        }
        __syncthreads();   // drains staging DMA for kt+1; protects buffer reuse
    }

    // ---- epilogue: l = own-half + partner-half via one permlane swap ----
    uint2v lt = __builtin_amdgcn_permlane32_swap(__float_as_uint(lsum), __float_as_uint(lsum), false, false);
    const float inv = 1.f / (__uint_as_float(lt.x) + __uint_as_float(lt.y));
    unsigned short* op = O + (size_t)(b * 2048 + qbase + l31) * 1024 + h * 64;
#pragma unroll
    for (int dsub = 0; dsub < 2; dsub++) {
#pragma unroll
        for (int q4 = 0; q4 < 4; q4++) {
            ushort4 pkv;
            pkv.x = f2bf(oacc[dsub][q4 * 4 + 0] * inv);
            pkv.y = f2bf(oacc[dsub][q4 * 4 + 1] * inv);
            pkv.z = f2bf(oacc[dsub][q4 * 4 + 2] * inv);
            pkv.w = f2bf(oacc[dsub][q4 * 4 + 3] * inv);
            *(ushort4*)(op + dsub * 32 + q4 * 8 + hi * 4) = pkv;
        }
    }
}

// ---------- launch ----------
extern "C" void kernel_launch(void* const* d_in, const int* in_sizes, int n_in,
                              void* d_out, int out_size, void* d_ws, size_t ws_size,
                              hipStream_t stream)
{
    const float* x   = (const float*)d_in[0];
    const float* q_w = (const float*)d_in[1];
    const float* q_b = (const float*)d_in[2];
    const float* k_w = (const float*)d_in[3];
    const float* k_b = (const float*)d_in[4];
    const float* v_w = (const float*)d_in[5];
    const float* v_b = (const float*)d_in[6];
    const float* o_w = (const float*)d_in[7];
    const float* o_b = (const float*)d_in[8];
    float* out = (float*)d_out;

    unsigned short* Xb   = (unsigned short*)d_ws;          // 8192*1024
    unsigned short* Wqkv = Xb + 8388608;                   // 3072*1024
    unsigned short* Owb  = Wqkv + 3145728;                 // 1024*1024
    float*          bqkv = (float*)(Owb + 1048576);        // 3072 fp32
    unsigned short* QK   = (unsigned short*)(bqkv + 3072); // 8192*2048
    unsigned short* Vtg  = QK + 16777216;                  // 64*64*2048 (transposed V)
    unsigned short* Abf  = Vtg + 8388608;                  // 8192*1024

    cvt_all<<<12291, 256, 0, stream>>>(x, q_w, k_w, v_w, o_w, q_b, k_b, v_b,
                                       Xb, Wqkv, Owb, bqkv);
    gemm256<1><<<dim3(32, 12), 512, 0, stream>>>(Xb, Wqkv, bqkv, QK, Vtg, 8192, 3072, 1024);
    attn_mfma<<<dim3(64, 16), 256, 0, stream>>>(QK, Vtg, Abf);
    gemm256<0><<<dim3(32, 4), 512, 0, stream>>>(Abf, Owb, o_b, out, nullptr, 8192, 1024, 1024);
}

// Round 3
// 255.151 us; speedup vs baseline: 1.0781x; 1.0781x over previous
//
#include <hip/hip_runtime.h>
#include <stdint.h>

typedef short short8 __attribute__((ext_vector_type(8)));
typedef float f32x4 __attribute__((ext_vector_type(4)));
typedef float f32x16 __attribute__((ext_vector_type(16)));
typedef unsigned int uint2v __attribute__((ext_vector_type(2)));
typedef unsigned int uint4v __attribute__((ext_vector_type(4)));

__device__ __forceinline__ unsigned short f2bf(float f) {
    unsigned int u = __float_as_uint(f);
    u += 0x7fffu + ((u >> 16) & 1u);   // round-to-nearest-even
    return (unsigned short)(u >> 16);
}

// async global->LDS, 16B per lane; lds base must be wave-uniform (HW adds lane*16)
__device__ __forceinline__ void gld_lds16(const unsigned short* g, unsigned short* l) {
    __builtin_amdgcn_global_load_lds((const __attribute__((address_space(1))) unsigned int*)g,
                                     (__attribute__((address_space(3))) unsigned int*)l,
                                     16, 0, 0);
}

// Q pre-scale: fold attn scale (1/8) and log2(e) into Q so attn softmax uses exp2 directly.
#define QSCL 0.18033688011112042f

// ---------- fused fp32->bf16 converts + bias concat (one dispatch) ----------
__global__ __launch_bounds__(256) void cvt_all(const float* __restrict__ x,
                                               const float* __restrict__ qw, const float* __restrict__ kw,
                                               const float* __restrict__ vw, const float* __restrict__ ow,
                                               const float* __restrict__ qb, const float* __restrict__ kb,
                                               const float* __restrict__ vb,
                                               unsigned short* __restrict__ Xb,
                                               unsigned short* __restrict__ Wqkv,
                                               unsigned short* __restrict__ Owb,
                                               float* __restrict__ bqkv) {
    int i = blockIdx.x * 256 + threadIdx.x;     // float4 index
    const float* src; uint2* dst; int j;
    if (i < 2097152)      { src = x;  dst = (uint2*)Xb;                j = i; }
    else if (i < 2359296) { src = qw; dst = (uint2*)Wqkv;              j = i - 2097152; }
    else if (i < 2621440) { src = kw; dst = (uint2*)(Wqkv + 1048576);  j = i - 2359296; }
    else if (i < 2883584) { src = vw; dst = (uint2*)(Wqkv + 2097152);  j = i - 2621440; }
    else if (i < 3145728) { src = ow; dst = (uint2*)Owb;               j = i - 2883584; }
    else {
        int t = i - 3145728;          // 0..767 : fp32 bias copies
        const float4* bs = (t < 256) ? (const float4*)qb : (t < 512) ? (const float4*)kb : (const float4*)vb;
        ((float4*)bqkv)[t] = bs[t & 255];
        return;
    }
    float4 v = ((const float4*)src)[j];
    unsigned int lo = (unsigned int)f2bf(v.x) | ((unsigned int)f2bf(v.y) << 16);
    unsigned int hi = (unsigned int)f2bf(v.z) | ((unsigned int)f2bf(v.w) << 16);
    dst[j] = make_uint2(lo, hi);
}

// ---------- bf16 NT GEMM: C[M,N] = A[M,K] @ B[N,K]^T + bias[N] ----------
// 128x128 tile, BK=64, 4 waves, global_load_lds(16) staging, xor-swizzled LDS (m97 structure).
// MODE 0: C0 = fp32 [M][N].
// MODE 1 (QKV): col<1024 -> bf16 Q (pre-scaled by QSCL); col<2048 -> bf16 K; col>=2048 -> Vt transposed.
template<int MODE>
__global__ __launch_bounds__(256) void gemm_bt(const unsigned short* __restrict__ A,
                                               const unsigned short* __restrict__ Bm,
                                               const float* __restrict__ bias,
                                               void* __restrict__ C0,
                                               unsigned short* __restrict__ VtOut,
                                               int M, int N, int K)
{
    __shared__ __align__(16) unsigned short As[128 * 64];
    __shared__ __align__(16) unsigned short Bs[128 * 64];
    const int tid  = threadIdx.x;
    const int bm   = blockIdx.x, bn = blockIdx.y;
    const int lane = tid & 63, w = tid >> 6;
    const int wm   = w >> 1, wn = w & 1;
    const int quad = lane >> 4, l15 = lane & 15;

    f32x4 acc[4][4];
#pragma unroll
    for (int mt = 0; mt < 4; mt++)
#pragma unroll
        for (int nt = 0; nt < 4; nt++)
            acc[mt][nt] = (f32x4){0.f, 0.f, 0.f, 0.f};

    const int kTiles = K >> 6;
    for (int kt = 0; kt < kTiles; ++kt) {
        __syncthreads();
#pragma unroll
        for (int i = 0; i < 4; i++) {
            int G  = i * 256 + tid;
            int m  = G >> 3, g = G & 7;
            int gs = g ^ (m & 7);
            int Gb = i * 256 + (w << 6);
            gld_lds16(A  + (size_t)(bm * 128 + m) * K + kt * 64 + gs * 8, &As[Gb * 8]);
            gld_lds16(Bm + (size_t)(bn * 128 + m) * K + kt * 64 + gs * 8, &Bs[Gb * 8]);
        }
        __syncthreads();
#pragma unroll
        for (int ks = 0; ks < 2; ++ks) {
            short8 af[4], bfr[4];
#pragma unroll
            for (int mt = 0; mt < 4; mt++) {
                int m = wm * 64 + mt * 16 + l15;
                af[mt] = *(const short8*)&As[m * 64 + (((ks * 4 + quad) ^ (l15 & 7)) << 3)];
            }
#pragma unroll
            for (int nt = 0; nt < 4; nt++) {
                int n = wn * 64 + nt * 16 + l15;
                bfr[nt] = *(const short8*)&Bs[n * 64 + (((ks * 4 + quad) ^ (l15 & 7)) << 3)];
            }
#pragma unroll
            for (int mt = 0; mt < 4; mt++)
#pragma unroll
                for (int nt = 0; nt < 4; nt++)
                    acc[mt][nt] = __builtin_amdgcn_mfma_f32_16x16x32_bf16(af[mt], bfr[nt], acc[mt][nt], 0, 0, 0);
        }
    }
    // epilogue: D row = quad*4+reg, col = l15
    const int row0 = bm * 128 + wm * 64, col0 = bn * 128 + wn * 64;
#pragma unroll
    for (int nt = 0; nt < 4; nt++) {
        int col = col0 + nt * 16 + l15;
        float bv = bias[col];
#pragma unroll
        for (int mt = 0; mt < 4; mt++) {
            if (MODE == 1 && col >= 2048) {
                // V: write transposed Vt[(b*1024 + (col-2048))*2048 + t]
                int row = row0 + mt * 16 + quad * 4;
                int b = row >> 11, t = row & 2047;
                ushort4 pk;
                pk.x = f2bf(acc[mt][nt][0] + bv);
                pk.y = f2bf(acc[mt][nt][1] + bv);
                pk.z = f2bf(acc[mt][nt][2] + bv);
                pk.w = f2bf(acc[mt][nt][3] + bv);
                *(ushort4*)(VtOut + (size_t)(b * 1024 + (col - 2048)) * 2048 + t) = pk;
            } else {
#pragma unroll
                for (int r = 0; r < 4; r++) {
                    int row = row0 + mt * 16 + quad * 4 + r;
                    float v = acc[mt][nt][r] + bv;
                    if (MODE == 1) {
                        if (col < 1024) v *= QSCL;
                        ((unsigned short*)C0)[(size_t)row * 2048 + col] = f2bf(v);
                    } else {
                        ((float*)C0)[(size_t)row * N + col] = v;
                    }
                }
            }
        }
    }
}

// ---------- MFMA causal flash attention, 32x32 tiles, in-register softmax ----------
// QK: (8192, 2048) bf16 rows = (b,t), cols [0,1024)=Q (pre-scaled by QSCL), [1024,2048)=K.
// Vt: [b*16+h][d][t] bf16. Block 256 = 4 waves; wave owns 32 q rows. Grid (64 bh, 16 qtiles).
// Pipeline (T3/T4): K/V TRIPLE-buffered in LDS (48 KiB). Per tile kt: counted s_waitcnt
// vmcnt(4) (tile kt's 4 loads done, kt+1's still in flight) -> raw s_barrier -> issue stage
// of tile kt+2 -> compute tile kt. No vmcnt(0) drain in the loop; two tiles of HBM latency
// covered. Buffer safety: stage target (kt+2)%3 != compute buffer kt%3; barrier orders the
// last reader of the slot (compute kt-1) before its overwrite.
// S^T = K@Q^T via mfma_32x32x16; lane holds 16 P of one q-col; exp2 -> perm-pack bf16 ->
// permlane32_swap builds PV B-frags in registers. l via VALU tree-sum + one permlane swap.
// Fixed-max softmax: p = exp2(s) directly (scores bounded; constant max cancels in O/l).
#define NEG_RAW (-1e30f)
__global__ __launch_bounds__(256, 4) void attn_mfma(const unsigned short* __restrict__ QK,
                                                    const unsigned short* __restrict__ Vt,
                                                    unsigned short* __restrict__ O)
{
    __shared__ __align__(16) unsigned short Kb[3][64 * 64];
    __shared__ __align__(16) unsigned short Vb[3][64 * 64];
    const int tid  = threadIdx.x;
    const int lane = tid & 63, w = tid >> 6;
    const int hi   = lane >> 5, l31 = lane & 31;
    const int s7   = lane & 7;
    const int bh   = blockIdx.x;
    const int b    = bh >> 4, h = bh & 15;
    const int qt   = (int)gridDim.y - 1 - (int)blockIdx.y;   // longest first
    const int qbase = qt * 128 + w * 32;                     // this wave's first q row

    const unsigned short* Qp = QK + (size_t)(b * 2048) * 2048 + h * 64;
    const unsigned short* Kp = Qp + 1024;
    const unsigned short* Vp = Vt + (size_t)(bh * 64) * 2048;

    // Q B-fragments (32x32x16): col q = l31, k = dk*16 + hi*8 + j
    short8 qf[4];
    {
        const unsigned short* qrow = Qp + (size_t)(qbase + l31) * 2048 + hi * 8;
#pragma unroll
        for (int dk = 0; dk < 4; dk++)
            qf[dk] = *(const short8*)(qrow + dk * 16);
    }

    f32x16 oacc[2];   // O^T: oacc[dsub], row d = dsub*32 + (r&3)+8*(r>>2)+4*hi, col q = l31
#pragma unroll
    for (int i = 0; i < 2; i++)
#pragma unroll
        for (int r = 0; r < 16; r++) oacc[i][r] = 0.f;
    float lsum = 0.f;

    const int ktend   = 2 * qt + 1;               // block processes keys [0, (qt+1)*128)
    const int ktmax_w = (qbase + 31) >> 6;        // last tile this wave computes on

    // stage tile t (keys [t*64,(t+1)*64)) into buffer bi: 2 K + 2 V gld_lds16 per thread
    auto stage = [&](int t, int bi) {
#pragma unroll
        for (int i = 0; i < 2; i++) {
            int G = i * 256 + tid;
            int r = G >> 3, g = G & 7, gs = g ^ (r & 7);
            int Gb = i * 256 + (w << 6);
            gld_lds16(Kp + (size_t)(t * 64 + r) * 2048 + gs * 8, &Kb[bi][Gb * 8]);
            gld_lds16(Vp + (size_t)r * 2048 + t * 64 + gs * 8, &Vb[bi][Gb * 8]);
        }
    };

    // ---- prologue: tiles 0 and 1 in flight (8 loads/thread) ----
    stage(0, 0);
    stage(1, 1);

    int cur = 0;
    for (int kt = 0; kt <= ktend; ++kt) {
        // tile kt's loads done; tile kt+1's (if staged) stay in flight
        if (kt < ktend) asm volatile("s_waitcnt vmcnt(4)" ::: "memory");
        else            asm volatile("s_waitcnt vmcnt(0)" ::: "memory");
        __builtin_amdgcn_sched_barrier(0);
        __builtin_amdgcn_s_barrier();
        __builtin_amdgcn_sched_barrier(0);
        // ---- issue stage of tile kt+2 (slot (cur+2)%3; its last reader was compute kt-1) ----
        if (kt + 2 <= ktend) {
            int bi = cur + 2; if (bi >= 3) bi -= 3;
            stage(kt + 2, bi);
        }
        // ---- compute on buffer cur ----
        if (kt <= ktmax_w) {
            __builtin_amdgcn_s_setprio(1);
            const unsigned short* Kc = Kb[cur];
            const unsigned short* Vc = Vb[cur];
            const int kbase = kt * 64;
#pragma unroll
            for (int sub = 0; sub < 2; sub++) {
                const int kb0 = kbase + sub * 32;
                if (kb0 > qbase + 31) continue;          // subtile fully masked
                // ---- S^T (32 keys x 32 q) ----
                f32x16 sacc;
#pragma unroll
                for (int r = 0; r < 16; r++) sacc[r] = 0.f;
                const unsigned short* kr = &Kc[(sub * 32 + l31) * 64];
#pragma unroll
                for (int dk = 0; dk < 4; dk++) {
                    short8 kf = *(const short8*)(kr + (((dk * 2 + hi) ^ s7) << 3));
                    sacc = __builtin_amdgcn_mfma_f32_32x32x16_bf16(kf, qf[dk], sacc, 0, 0, 0);
                }
                // ---- causal mask (diag subtile only) ----
                if (kb0 + 31 > qbase) {
                    const int qg = qbase + l31;
                    const int kb = kb0 + 4 * hi;
#pragma unroll
                    for (int r = 0; r < 16; r++) {
                        int key = kb + (r & 3) + 8 * (r >> 2);
                        if (key > qg) sacc[r] = NEG_RAW;
                    }
                }
                // ---- p = exp2(s); l partial sum ----
#pragma unroll
                for (int r = 0; r < 16; r++) sacc[r] = __builtin_exp2f(sacc[r]);
                {
                    float s0 = (sacc[0] + sacc[1]) + (sacc[2] + sacc[3]);
                    float s1 = (sacc[4] + sacc[5]) + (sacc[6] + sacc[7]);
                    float s2 = (sacc[8] + sacc[9]) + (sacc[10] + sacc[11]);
                    float s3 = (sacc[12] + sacc[13]) + (sacc[14] + sacc[15]);
                    lsum += (s0 + s1) + (s2 + s3);
                }
                // ---- pack pairs to bf16 (truncating perm), exchange halves -> PV B-frags ----
                unsigned int pk[8];
#pragma unroll
                for (int t2 = 0; t2 < 8; t2++)
                    pk[t2] = __builtin_amdgcn_perm(__float_as_uint(sacc[2 * t2 + 1]),
                                                   __float_as_uint(sacc[2 * t2]), 0x07060302u);
                uint2v r0 = __builtin_amdgcn_permlane32_swap(pk[0], pk[2], false, false);
                uint2v r1 = __builtin_amdgcn_permlane32_swap(pk[1], pk[3], false, false);
                uint2v r2 = __builtin_amdgcn_permlane32_swap(pk[4], pk[6], false, false);
                uint2v r3 = __builtin_amdgcn_permlane32_swap(pk[5], pk[7], false, false);
                short8 pf[2];
                { uint4v u; u.x = r0.x; u.y = r1.x; u.z = r0.y; u.w = r1.y; pf[0] = __builtin_bit_cast(short8, u); }
                { uint4v u; u.x = r2.x; u.y = r3.x; u.z = r2.y; u.w = r3.y; pf[1] = __builtin_bit_cast(short8, u); }
                // ---- O^T += V^T @ P^T ----
#pragma unroll
                for (int kv = 0; kv < 2; kv++) {
#pragma unroll
                    for (int dsub = 0; dsub < 2; dsub++) {
                        const int d = dsub * 32 + l31;
                        short8 vf = *(const short8*)&Vc[d * 64 + (((sub * 4 + kv * 2 + hi) ^ s7) << 3)];
                        oacc[dsub] = __builtin_amdgcn_mfma_f32_32x32x16_bf16(vf, pf[kv], oacc[dsub], 0, 0, 0);
                    }
                }
            }
            __builtin_amdgcn_s_setprio(0);
        }
        cur = (cur == 2) ? 0 : cur + 1;
    }

    // ---- epilogue: l = own-half + partner-half via one permlane swap ----
    uint2v lt = __builtin_amdgcn_permlane32_swap(__float_as_uint(lsum), __float_as_uint(lsum), false, false);
    const float inv = 1.f / (__uint_as_float(lt.x) + __uint_as_float(lt.y));
    unsigned short* op = O + (size_t)(b * 2048 + qbase + l31) * 1024 + h * 64;
#pragma unroll
    for (int dsub = 0; dsub < 2; dsub++) {
#pragma unroll
        for (int q4 = 0; q4 < 4; q4++) {
            ushort4 pkv;
            pkv.x = f2bf(oacc[dsub][q4 * 4 + 0] * inv);
            pkv.y = f2bf(oacc[dsub][q4 * 4 + 1] * inv);
            pkv.z = f2bf(oacc[dsub][q4 * 4 + 2] * inv);
            pkv.w = f2bf(oacc[dsub][q4 * 4 + 3] * inv);
            *(ushort4*)(op + dsub * 32 + q4 * 8 + hi * 4) = pkv;
        }
    }
}

// ---------- launch ----------
extern "C" void kernel_launch(void* const* d_in, const int* in_sizes, int n_in,
                              void* d_out, int out_size, void* d_ws, size_t ws_size,
                              hipStream_t stream)
{
    const float* x   = (const float*)d_in[0];
    const float* q_w = (const float*)d_in[1];
    const float* q_b = (const float*)d_in[2];
    const float* k_w = (const float*)d_in[3];
    const float* k_b = (const float*)d_in[4];
    const float* v_w = (const float*)d_in[5];
    const float* v_b = (const float*)d_in[6];
    const float* o_w = (const float*)d_in[7];
    const float* o_b = (const float*)d_in[8];
    float* out = (float*)d_out;

    unsigned short* Xb   = (unsigned short*)d_ws;          // 8192*1024
    unsigned short* Wqkv = Xb + 8388608;                   // 3072*1024
    unsigned short* Owb  = Wqkv + 3145728;                 // 1024*1024
    float*          bqkv = (float*)(Owb + 1048576);        // 3072 fp32
    unsigned short* QK   = (unsigned short*)(bqkv + 3072); // 8192*2048
    unsigned short* Vtg  = QK + 16777216;                  // 64*64*2048 (transposed V)
    unsigned short* Abf  = Vtg + 8388608;                  // 8192*1024

    cvt_all<<<12291, 256, 0, stream>>>(x, q_w, k_w, v_w, o_w, q_b, k_b, v_b,
                                       Xb, Wqkv, Owb, bqkv);
    gemm_bt<1><<<dim3(64, 24), 256, 0, stream>>>(Xb, Wqkv, bqkv, QK, Vtg, 8192, 3072, 1024);
    attn_mfma<<<dim3(64, 16), 256, 0, stream>>>(QK, Vtg, Abf);
    gemm_bt<0><<<dim3(64, 8), 256, 0, stream>>>(Abf, Owb, o_b, out, nullptr, 8192, 1024, 1024);
}